// Round 5
// baseline (183.839 us; speedup 1.0000x reference)
//
#include <hip/hip_runtime.h>
#include <hip/hip_bf16.h>

#define B_ 4
#define N_ 4096
#define D_ 128
#define EPB (N_ * D_)        // elems per batch in packed layout = 524288
#define CHUNKS 8             // column chunks per batch
#define STEPS 8              // 64-col steps per chunk (8*64*8 = 4096)
#define COFF 1024.0f         // colmin positivity offset (Cauchy-Schwarz bound ~250)

typedef short short8 __attribute__((ext_vector_type(8)));
typedef float f32x4 __attribute__((ext_vector_type(4)));

#define SQRT2 1.41421356237309515f

typedef const __attribute__((address_space(1))) void gvoid_t;
typedef __attribute__((address_space(3))) void lvoid_t;

// ---------------------------------------------------------------------------
// Packed fragment-major layout (per batch):
//   elem(row, k) -> (row>>4)*2048 + (k>>3)*128 + (row&15)*8 + (k&7)
// -> a 64-col (4 row-group) tile is 16 KB CONTIGUOUS; a wave MFMA fragment is
// a contiguous 1 KB slice at lane*16 B.
// ---------------------------------------------------------------------------

__device__ __forceinline__ unsigned pack2_bf16_sqrt2(float a, float b) {
    const unsigned ua = __float_as_uint(a * SQRT2);
    const unsigned ub = __float_as_uint(b * SQRT2);
    const unsigned ra = (ua + 0x7fffu + ((ua >> 16) & 1u)) >> 16;
    const unsigned rb = (ub + 0x7fffu + ((ub >> 16) & 1u)) >> 16;
    return ra | (rb << 16);
}

// ---------------------------------------------------------------------------
// Kernel 1: fp32 -> bf16*sqrt2 into packed layout + row norms + min init.
// One block per 16-row group. Thread t: row r=t&15, k-chunk c=t>>4 (8 elems).
// Packed writes are wave-contiguous 1 KB. Norms via LDS (no bpermute chains).
// ---------------------------------------------------------------------------
__global__ __launch_bounds__(256) void prep_kernel(
    const float* __restrict__ X, const float* __restrict__ Y,
    unsigned short* __restrict__ Xb, unsigned short* __restrict__ Yb,
    float* __restrict__ x2, float* __restrict__ y2,
    int* __restrict__ rowmin, int* __restrict__ colmin)
{
    const int which = blockIdx.y;
    const float* __restrict__ src = which ? Y : X;
    unsigned short* __restrict__ dst = which ? Yb : Xb;
    float* __restrict__ nrm = which ? y2 : x2;
    int* __restrict__ mn = which ? colmin : rowmin;

    const int t = threadIdx.x;
    const int r = t & 15, c = t >> 4;          // c in 0..15
    const int rgG = blockIdx.x;                // 0..1023 (global row-group)
    const int row = rgG * 16 + r;              // 0..16383

    const float4 v0 = *(const float4*)(src + (size_t)row * D_ + c * 8);
    const float4 v1 = *(const float4*)(src + (size_t)row * D_ + c * 8 + 4);

    float sq = v0.x * v0.x;
    sq = fmaf(v0.y, v0.y, sq); sq = fmaf(v0.z, v0.z, sq); sq = fmaf(v0.w, v0.w, sq);
    sq = fmaf(v1.x, v1.x, sq); sq = fmaf(v1.y, v1.y, sq);
    sq = fmaf(v1.z, v1.z, sq); sq = fmaf(v1.w, v1.w, sq);

    uint4 packed;
    packed.x = pack2_bf16_sqrt2(v0.x, v0.y);
    packed.y = pack2_bf16_sqrt2(v0.z, v0.w);
    packed.z = pack2_bf16_sqrt2(v1.x, v1.y);
    packed.w = pack2_bf16_sqrt2(v1.z, v1.w);

    const int b = row >> 12;                   // row / N_
    const int rg = (row & (N_ - 1)) >> 4;
    unsigned short* dbase = dst + (size_t)b * EPB + rg * 2048;
    *(uint4*)(dbase + c * 128 + r * 8) = packed;   // wave writes 1KB contiguous

    __shared__ float s[256];
    s[r * 16 + c] = sq;
    __syncthreads();
    if (t < 16) {      // t == r
        const float4* sp = (const float4*)(s + t * 16);
        float4 a = sp[0], bq = sp[1], cq = sp[2], d = sp[3];
        float tot = a.x + a.y + a.z + a.w + bq.x + bq.y + bq.z + bq.w
                  + cq.x + cq.y + cq.z + cq.w + d.x + d.y + d.z + d.w;
        nrm[rgG * 16 + t] = tot;
        mn[rgG * 16 + t] = 0x7f7fffff;   // +FLT_MAX bits
    }
}

// ---------------------------------------------------------------------------
// Kernel 2: persistent row-stripe MFMA chamfer.
// Block = 4 waves x 64 rows = 256 rows; sweeps STEPS column-tiles of 64.
// A frags resident in regs (64 VGPR/wave); B tile (16 KB contiguous) staged
// per step via global_load_lds, double-buffered; per-step barrier drain lands
// after a full step of compute overlap.
// acc == 2*zz (inputs pre-scaled by sqrt2).
//   rmin_i  = min_j (y2_j - acc) accumulated in regs across sweep,
//             emitted once: clamp(x2_i + rmin).
//   cmin_j  = min_i (x2_i - acc) per step in regs, emitted after loop as
//             (cmin + 1024) WITHOUT y2 (finalize adds y2 & clamps).
//   C/D layout: row = quad*4 + reg, col = l16   [m89-verified]
// ---------------------------------------------------------------------------
__global__ __launch_bounds__(256, 2) void chamfer_mfma(
    const unsigned short* __restrict__ Xb, const unsigned short* __restrict__ Yb,
    const float* __restrict__ x2, const float* __restrict__ y2,
    int* __restrict__ rowmin, int* __restrict__ colmin)
{
    __shared__ char lds[2 * 16384];

    const int b = blockIdx.z;
    const int stripe = blockIdx.y;       // 0..15
    const int chunk = blockIdx.x;        // 0..CHUNKS-1
    const int tid = threadIdx.x;
    const int wave = tid >> 6, lane = tid & 63;
    const int quad = lane >> 4, l16 = lane & 15;

    const int rowBase = stripe * 256 + wave * 64;
    const int colChunkBase = chunk * (STEPS * 64);

    const unsigned short* __restrict__ Xp = Xb + (size_t)b * EPB;
    const unsigned short* __restrict__ Yp = Yb + (size_t)b * EPB;

    // ---- A fragments: resident across the sweep (16 x short8 = 64 VGPR) ----
    short8 af[4][4];   // [rt][kc]
    #pragma unroll
    for (int rt = 0; rt < 4; rt++) {
        const unsigned short* ap = Xp + ((rowBase >> 4) + rt) * 2048 + lane * 8;
        #pragma unroll
        for (int kc = 0; kc < 4; kc++)
            af[rt][kc] = *(const short8*)(ap + kc * 512);
    }
    // x2 of own rows (row = rowBase + rt*16 + quad*4 + i)
    float x2v[4][4];
    #pragma unroll
    for (int rt = 0; rt < 4; rt++)
        #pragma unroll
        for (int i = 0; i < 4; i++)
            x2v[rt][i] = x2[(size_t)b * N_ + rowBase + rt * 16 + quad * 4 + i];

    // ---- stage helper: B tile for step s is 16 KB contiguous ----
    // per wave: 4 x global_load_lds(16B/lane) covering wave*4KB..+4KB
#define STAGE(sidx, buf) do {                                                  \
        const char* gb = (const char*)Yp                                       \
            + (size_t)(colChunkBase + (sidx) * 64) * 256 + wave * 4096 + lane * 16; \
        char* lb = lds + (buf) * 16384 + wave * 4096;                          \
        _Pragma("unroll")                                                      \
        for (int c_ = 0; c_ < 4; ++c_)                                         \
            __builtin_amdgcn_global_load_lds(                                  \
                (gvoid_t*)(gb + c_ * 1024), (lvoid_t*)(lb + c_ * 1024), 16, 0, 0); \
    } while (0)

    STAGE(0, 0);

    float rmin[4][4];
    float cminAll[STEPS][4];
    #pragma unroll
    for (int rt = 0; rt < 4; rt++)
        #pragma unroll
        for (int i = 0; i < 4; i++) rmin[rt][i] = 3.0e38f;
    #pragma unroll
    for (int s = 0; s < STEPS; s++)
        #pragma unroll
        for (int ct = 0; ct < 4; ct++) cminAll[s][ct] = 3.0e38f;

    __syncthreads();   // implicit vmcnt(0): stage(0) resident

    #pragma unroll
    for (int s = 0; s < STEPS; ++s) {
        const int cur = s & 1;
        if (s + 1 < STEPS) STAGE(s + 1, cur ^ 1);   // prefetch, drained at next barrier

        // y2 of this step's cols (col = colChunkBase + s*64 + ct*16 + l16)
        float y2v[4];
        #pragma unroll
        for (int ct = 0; ct < 4; ct++)
            y2v[ct] = y2[(size_t)b * N_ + colChunkBase + s * 64 + ct * 16 + l16];

        f32x4 acc[4][4];
        #pragma unroll
        for (int i = 0; i < 4; i++)
            #pragma unroll
            for (int j = 0; j < 4; j++)
                acc[i][j] = (f32x4){0.f, 0.f, 0.f, 0.f};

        #pragma unroll
        for (int kc = 0; kc < 4; kc++) {
            short8 bfv[4];
            #pragma unroll
            for (int ct = 0; ct < 4; ct++)
                bfv[ct] = *(const short8*)(lds + cur * 16384 + ct * 4096
                                           + kc * 1024 + lane * 16);
            #pragma unroll
            for (int rt = 0; rt < 4; rt++)
                #pragma unroll
                for (int ct = 0; ct < 4; ct++)
                    acc[rt][ct] = __builtin_amdgcn_mfma_f32_16x16x32_bf16(
                        af[rt][kc], bfv[ct], acc[rt][ct], 0, 0, 0);
        }

        // folds (register-only): rmin over cols, cmin over rows
        #pragma unroll
        for (int rt = 0; rt < 4; rt++)
            #pragma unroll
            for (int i = 0; i < 4; i++) {
                const float xv = x2v[rt][i];
                float rm = rmin[rt][i];
                #pragma unroll
                for (int ct = 0; ct < 4; ct++) {
                    const float a = acc[rt][ct][i];
                    rm = fminf(rm, y2v[ct] - a);
                    cminAll[s][ct] = fminf(cminAll[s][ct], xv - a);
                }
                rmin[rt][i] = rm;
            }

        __syncthreads();   // all waves done reading buf[cur]; drains prefetch
    }
#undef STAGE

    // ---- rowmin emission (once per wave) ----
    #pragma unroll
    for (int rt = 0; rt < 4; rt++)
        #pragma unroll
        for (int i = 0; i < 4; i++) {
            float v = rmin[rt][i];
            #pragma unroll
            for (int m = 1; m < 16; m <<= 1) v = fminf(v, __shfl_xor(v, m));
            rmin[rt][i] = v;
        }
    if (l16 == 0) {
        #pragma unroll
        for (int rt = 0; rt < 4; rt++)
            #pragma unroll
            for (int i = 0; i < 4; i++) {
                float v = fminf(fmaxf(x2v[rt][i] + rmin[rt][i], 0.0f), 100.0f);
                atomicMin(&rowmin[(size_t)b * N_ + rowBase + rt * 16 + quad * 4 + i],
                          __float_as_int(v));
            }
    }

    // ---- colmin emission: raw (no y2), +1024 to stay positive ----
    #pragma unroll
    for (int s = 0; s < STEPS; s++) {
        #pragma unroll
        for (int ct = 0; ct < 4; ct++) {
            float v = cminAll[s][ct];
            v = fminf(v, __shfl_xor(v, 16));
            v = fminf(v, __shfl_xor(v, 32));
            if (quad == 0)
                atomicMin(&colmin[(size_t)b * N_ + colChunkBase + s * 64 + ct * 16 + l16],
                          __float_as_int(v + COFF));
        }
    }
}

// ---------------------------------------------------------------------------
// Kernel 3: final mean. rowmin holds clamped values; colmin holds
// (min_i(x2_i - acc) + 1024) -> add y2, subtract offset, clamp here.
// out = (sum_rowmin + sum_colmin) / (B*N) / B
// ---------------------------------------------------------------------------
__global__ __launch_bounds__(1024) void finalize_kernel(
    const int* __restrict__ rowmin, const int* __restrict__ colmin,
    const float* __restrict__ y2, float* __restrict__ out)
{
    float s = 0.f;
    for (int i = threadIdx.x; i < B_ * N_ / 4; i += 1024) {
        int4 v = ((const int4*)rowmin)[i];
        s += __int_as_float(v.x) + __int_as_float(v.y) +
             __int_as_float(v.z) + __int_as_float(v.w);
        int4 c = ((const int4*)colmin)[i];
        float4 yv = ((const float4*)y2)[i];
        s += fminf(fmaxf(__int_as_float(c.x) - COFF + yv.x, 0.f), 100.f);
        s += fminf(fmaxf(__int_as_float(c.y) - COFF + yv.y, 0.f), 100.f);
        s += fminf(fmaxf(__int_as_float(c.z) - COFF + yv.z, 0.f), 100.f);
        s += fminf(fmaxf(__int_as_float(c.w) - COFF + yv.w, 0.f), 100.f);
    }
    #pragma unroll
    for (int m = 1; m < 64; m <<= 1) s += __shfl_xor(s, m);
    __shared__ float sm[16];
    if ((threadIdx.x & 63) == 0) sm[threadIdx.x >> 6] = s;
    __syncthreads();
    if (threadIdx.x == 0) {
        float t = 0.f;
        #pragma unroll
        for (int i = 0; i < 16; i++) t += sm[i];
        out[0] = t / ((float)B_ * (float)N_) / (float)B_;
    }
}

extern "C" void kernel_launch(void* const* d_in, const int* in_sizes, int n_in,
                              void* d_out, int out_size, void* d_ws, size_t ws_size,
                              hipStream_t stream) {
    const float* X = (const float*)d_in[0];   // corr_pred   [B,N,D] fp32
    const float* Y = (const float*)d_in[1];   // corr_target [B,N,D] fp32

    char* ws = (char*)d_ws;
    const size_t bf_bytes = (size_t)B_ * N_ * D_ * 2;   // 4 MB each (packed)
    unsigned short* Xb = (unsigned short*)ws;
    unsigned short* Yb = (unsigned short*)(ws + bf_bytes);
    char* ws2 = ws + 2 * bf_bytes;
    const size_t vec_bytes = (size_t)B_ * N_ * 4;       // 64 KB each
    float* x2     = (float*)(ws2);
    float* y2     = (float*)(ws2 + vec_bytes);
    int*   rowmin = (int*)  (ws2 + 2 * vec_bytes);
    int*   colmin = (int*)  (ws2 + 3 * vec_bytes);
    float* out = (float*)d_out;

    prep_kernel<<<dim3(B_ * N_ / 16, 2), 256, 0, stream>>>(
        X, Y, Xb, Yb, x2, y2, rowmin, colmin);
    chamfer_mfma<<<dim3(CHUNKS, N_ / 256, B_), 256, 0, stream>>>(
        Xb, Yb, x2, y2, rowmin, colmin);
    finalize_kernel<<<1, 1024, 0, stream>>>(rowmin, colmin, y2, out);
}

// Round 6
// 106.793 us; speedup vs baseline: 1.7214x; 1.7214x over previous
//
#include <hip/hip_runtime.h>
#include <hip/hip_bf16.h>

#define B_ 4
#define N_ 4096
#define D_ 128
#define EPB (N_ * D_)        // elems per batch in packed layout = 524288
#define COFF 1024.0f         // colmin positivity offset

typedef short short8 __attribute__((ext_vector_type(8)));
typedef float f32x4 __attribute__((ext_vector_type(4)));

#define SQRT2 1.41421356237309515f

// ---------------------------------------------------------------------------
// Packed fragment-major layout (per batch):
//   elem(row, k) -> (row>>4)*2048 + (k>>3)*128 + (row&15)*8 + (k&7)
// A wave's MFMA fragment for row-group rg, k-chunk kc is the contiguous 1 KB
// at rg*2048 + kc*512 + lane*8  -- one coalesced dwordx4 per lane.
// ---------------------------------------------------------------------------

__device__ __forceinline__ unsigned pack2_bf16_sqrt2(float a, float b) {
    const unsigned ua = __float_as_uint(a * SQRT2);
    const unsigned ub = __float_as_uint(b * SQRT2);
    const unsigned ra = (ua + 0x7fffu + ((ua >> 16) & 1u)) >> 16;
    const unsigned rb = (ub + 0x7fffu + ((ub >> 16) & 1u)) >> 16;
    return ra | (rb << 16);
}

// ---------------------------------------------------------------------------
// Kernel 1: fp32 -> bf16*sqrt2 into packed layout + row norms + min init.
// One block per 16-row group. Thread t: row r=t&15, k-chunk c=t>>4 (8 elems).
// ---------------------------------------------------------------------------
__global__ __launch_bounds__(256) void prep_kernel(
    const float* __restrict__ X, const float* __restrict__ Y,
    unsigned short* __restrict__ Xb, unsigned short* __restrict__ Yb,
    float* __restrict__ x2, float* __restrict__ y2,
    int* __restrict__ rowmin, int* __restrict__ colmin)
{
    const int which = blockIdx.y;
    const float* __restrict__ src = which ? Y : X;
    unsigned short* __restrict__ dst = which ? Yb : Xb;
    float* __restrict__ nrm = which ? y2 : x2;
    int* __restrict__ mn = which ? colmin : rowmin;

    const int t = threadIdx.x;
    const int r = t & 15, c = t >> 4;          // c in 0..15
    const int rgG = blockIdx.x;                // global row-group
    const int row = rgG * 16 + r;

    const float4 v0 = *(const float4*)(src + (size_t)row * D_ + c * 8);
    const float4 v1 = *(const float4*)(src + (size_t)row * D_ + c * 8 + 4);

    float sq = v0.x * v0.x;
    sq = fmaf(v0.y, v0.y, sq); sq = fmaf(v0.z, v0.z, sq); sq = fmaf(v0.w, v0.w, sq);
    sq = fmaf(v1.x, v1.x, sq); sq = fmaf(v1.y, v1.y, sq);
    sq = fmaf(v1.z, v1.z, sq); sq = fmaf(v1.w, v1.w, sq);

    uint4 packed;
    packed.x = pack2_bf16_sqrt2(v0.x, v0.y);
    packed.y = pack2_bf16_sqrt2(v0.z, v0.w);
    packed.z = pack2_bf16_sqrt2(v1.x, v1.y);
    packed.w = pack2_bf16_sqrt2(v1.z, v1.w);

    const int b = row >> 12;
    const int rg = (row & (N_ - 1)) >> 4;
    unsigned short* dbase = dst + (size_t)b * EPB + rg * 2048;
    *(uint4*)(dbase + c * 128 + r * 8) = packed;

    __shared__ float s[256];
    s[r * 16 + c] = sq;
    __syncthreads();
    if (t < 16) {
        const float4* sp = (const float4*)(s + t * 16);
        float4 a = sp[0], bq = sp[1], cq = sp[2], d = sp[3];
        float tot = a.x + a.y + a.z + a.w + bq.x + bq.y + bq.z + bq.w
                  + cq.x + cq.y + cq.z + cq.w + d.x + d.y + d.z + d.w;
        nrm[rgG * 16 + t] = tot;
        mn[rgG * 16 + t] = 0x7f7fffff;   // +FLT_MAX bits
    }
}

// ---------------------------------------------------------------------------
// Kernel 2: stripe-sweep MFMA chamfer. NO LDS, NO barriers, NO spill.
// Block = 4 waves; rows: iT*128 + (wave>>1)*64 resident for whole block.
// Sweeps 4 steps of 128 cols (jChunk = 512 cols). A-frags loaded once
// (64 VGPR); B-frags in 8-load half-steps (32 VGPR); acc 64 (AGPR-eligible);
// rmin persists in regs across the sweep; cmin reduced+atomic'd per step.
// Grid x = jChunk so same-stripe blocks share an XCD (id % 8) -> B reads
// are XCD-L2-local.
//   acc == 2*zz (inputs pre-scaled by sqrt2); P = x2 + y2 - acc.
//   C/D layout: row = quad*4 + reg, col = l16   [m89-verified]
// ---------------------------------------------------------------------------
__global__ __launch_bounds__(256, 2) void chamfer_mfma(
    const unsigned short* __restrict__ Xb, const unsigned short* __restrict__ Yb,
    const float* __restrict__ x2, const float* __restrict__ y2,
    int* __restrict__ rowmin, int* __restrict__ colmin)
{
    const int b = blockIdx.z;
    const int iT = blockIdx.y;           // 0..31
    const int jc = blockIdx.x;           // 0..7   (512-col chunk)
    const int tid = threadIdx.x;
    const int wave = tid >> 6, lane = tid & 63;
    const int quad = lane >> 4, l16 = lane & 15;
    const int wr = wave >> 1, wc = wave & 1;
    const int rowBase = iT * 128 + wr * 64;

    const unsigned short* __restrict__ Xp = Xb + (size_t)b * EPB;
    const unsigned short* __restrict__ Yp = Yb + (size_t)b * EPB;

    // ---- A fragments resident (16 x short8 = 64 VGPR) ----
    short8 af[4][4];   // [rt][kc]
    #pragma unroll
    for (int rt = 0; rt < 4; rt++) {
        const unsigned short* ap = Xp + ((rowBase >> 4) + rt) * 2048 + lane * 8;
        #pragma unroll
        for (int kc = 0; kc < 4; kc++)
            af[rt][kc] = *(const short8*)(ap + kc * 512);
    }
    float x2v[4][4];   // row = rowBase + rt*16 + quad*4 + i
    #pragma unroll
    for (int rt = 0; rt < 4; rt++)
        #pragma unroll
        for (int i = 0; i < 4; i++)
            x2v[rt][i] = x2[(size_t)b * N_ + rowBase + rt * 16 + quad * 4 + i];

    float rmin[4][4];
    #pragma unroll
    for (int rt = 0; rt < 4; rt++)
        #pragma unroll
        for (int i = 0; i < 4; i++) rmin[rt][i] = 3.0e38f;

    for (int s = 0; s < 4; ++s) {
        const int colBase = jc * 512 + s * 128 + wc * 64;
        const int cg = colBase >> 4;               // column row-group index

        float y2v[4];
        #pragma unroll
        for (int ct = 0; ct < 4; ct++)
            y2v[ct] = y2[(size_t)b * N_ + colBase + ct * 16 + l16];

        f32x4 acc[4][4];
        #pragma unroll
        for (int i = 0; i < 4; i++)
            #pragma unroll
            for (int j = 0; j < 4; j++)
                acc[i][j] = (f32x4){0.f, 0.f, 0.f, 0.f};

        #pragma unroll
        for (int h = 0; h < 2; h++) {              // half-steps: kc = 2h, 2h+1
            short8 bfv[2][4];
            #pragma unroll
            for (int k2 = 0; k2 < 2; k2++)
                #pragma unroll
                for (int ct = 0; ct < 4; ct++)
                    bfv[k2][ct] = *(const short8*)(
                        Yp + (size_t)(cg + ct) * 2048 + (2 * h + k2) * 512 + lane * 8);
            #pragma unroll
            for (int k2 = 0; k2 < 2; k2++)
                #pragma unroll
                for (int rt = 0; rt < 4; rt++)
                    #pragma unroll
                    for (int ct = 0; ct < 4; ct++)
                        acc[rt][ct] = __builtin_amdgcn_mfma_f32_16x16x32_bf16(
                            af[rt][2 * h + k2], bfv[k2][ct], acc[rt][ct], 0, 0, 0);
        }

        // ---- fold: rmin over cols (persist); cmin over rows (emit now) ----
        float cmin[4];
        #pragma unroll
        for (int ct = 0; ct < 4; ct++) cmin[ct] = 3.0e38f;
        #pragma unroll
        for (int rt = 0; rt < 4; rt++)
            #pragma unroll
            for (int i = 0; i < 4; i++) {
                const float xv = x2v[rt][i];
                float rm = rmin[rt][i];
                #pragma unroll
                for (int ct = 0; ct < 4; ct++) {
                    const float a = acc[rt][ct][i];
                    rm = fminf(rm, y2v[ct] - a);
                    cmin[ct] = fminf(cmin[ct], xv - a);
                }
                rmin[rt][i] = rm;
            }
        #pragma unroll
        for (int ct = 0; ct < 4; ct++) {
            float v = cmin[ct];
            v = fminf(v, __shfl_xor(v, 16));
            v = fminf(v, __shfl_xor(v, 32));
            if (quad == 0)
                atomicMin(&colmin[(size_t)b * N_ + colBase + ct * 16 + l16],
                          __float_as_int(v + COFF));
        }
    }

    // ---- rowmin emission (once per block) ----
    #pragma unroll
    for (int rt = 0; rt < 4; rt++)
        #pragma unroll
        for (int i = 0; i < 4; i++) {
            float v = rmin[rt][i];
            #pragma unroll
            for (int m = 1; m < 16; m <<= 1) v = fminf(v, __shfl_xor(v, m));
            if (l16 == 0) {
                float c = fminf(fmaxf(x2v[rt][i] + v, 0.0f), 100.0f);
                atomicMin(&rowmin[(size_t)b * N_ + rowBase + rt * 16 + quad * 4 + i],
                          __float_as_int(c));
            }
        }
}

// ---------------------------------------------------------------------------
// Kernel 3: final mean, 16 blocks, fp32 atomicAdd into pre-zeroed out.
// rowmin holds clamped values; colmin holds (min_i(x2_i - acc) + COFF):
// add y2, subtract COFF, clamp here.
// ---------------------------------------------------------------------------
__global__ __launch_bounds__(256) void finalize_kernel(
    const int* __restrict__ rowmin, const int* __restrict__ colmin,
    const float* __restrict__ y2, float* __restrict__ out)
{
    const int i = blockIdx.x * 256 + threadIdx.x;   // 0..4095, covers B_*N_/4
    float s = 0.f;
    {
        int4 v = ((const int4*)rowmin)[i];
        s += __int_as_float(v.x) + __int_as_float(v.y) +
             __int_as_float(v.z) + __int_as_float(v.w);
        int4 c = ((const int4*)colmin)[i];
        float4 yv = ((const float4*)y2)[i];
        s += fminf(fmaxf(__int_as_float(c.x) - COFF + yv.x, 0.f), 100.f);
        s += fminf(fmaxf(__int_as_float(c.y) - COFF + yv.y, 0.f), 100.f);
        s += fminf(fmaxf(__int_as_float(c.z) - COFF + yv.z, 0.f), 100.f);
        s += fminf(fmaxf(__int_as_float(c.w) - COFF + yv.w, 0.f), 100.f);
    }
    #pragma unroll
    for (int m = 1; m < 64; m <<= 1) s += __shfl_xor(s, m);
    __shared__ float sm[4];
    if ((threadIdx.x & 63) == 0) sm[threadIdx.x >> 6] = s;
    __syncthreads();
    if (threadIdx.x == 0)
        atomicAdd(out, (sm[0] + sm[1] + sm[2] + sm[3])
                        * (1.0f / ((float)B_ * (float)N_ * (float)B_)));
}

extern "C" void kernel_launch(void* const* d_in, const int* in_sizes, int n_in,
                              void* d_out, int out_size, void* d_ws, size_t ws_size,
                              hipStream_t stream) {
    const float* X = (const float*)d_in[0];   // corr_pred   [B,N,D] fp32
    const float* Y = (const float*)d_in[1];   // corr_target [B,N,D] fp32

    char* ws = (char*)d_ws;
    const size_t bf_bytes = (size_t)B_ * N_ * D_ * 2;   // 4 MB each (packed)
    unsigned short* Xb = (unsigned short*)ws;
    unsigned short* Yb = (unsigned short*)(ws + bf_bytes);
    char* ws2 = ws + 2 * bf_bytes;
    const size_t vec_bytes = (size_t)B_ * N_ * 4;       // 64 KB each
    float* x2     = (float*)(ws2);
    float* y2     = (float*)(ws2 + vec_bytes);
    int*   rowmin = (int*)  (ws2 + 2 * vec_bytes);
    int*   colmin = (int*)  (ws2 + 3 * vec_bytes);
    float* out = (float*)d_out;

    prep_kernel<<<dim3(B_ * N_ / 16, 2), 256, 0, stream>>>(
        X, Y, Xb, Yb, x2, y2, rowmin, colmin);
    chamfer_mfma<<<dim3(8, N_ / 128, B_), 256, 0, stream>>>(
        Xb, Yb, x2, y2, rowmin, colmin);
    hipMemsetAsync(d_out, 0, sizeof(float), stream);
    finalize_kernel<<<dim3(B_ * N_ / 4 / 256), 256, 0, stream>>>(
        rowmin, colmin, y2, out);
}

// Round 7
// 95.892 us; speedup vs baseline: 1.9172x; 1.1137x over previous
//
#include <hip/hip_runtime.h>
#include <hip/hip_bf16.h>

#define B_ 4
#define N_ 4096
#define D_ 128
#define EPB (N_ * D_)        // BYTES per batch in packed fp8 layout = 524288
#define COFF 1024.0f         // colmin positivity offset

typedef float f32x4 __attribute__((ext_vector_type(4)));

#define SQRT2 1.41421356237309515f

// ---------------------------------------------------------------------------
// Packed fragment-major fp8 layout (per batch, BYTE addresses):
//   elem(row, k) -> (row>>4)*2048 + (k>>3)*128 + (row&15)*8 + (k&7)
// MFMA fragment (16x16x32 fp8): lane l16 = row, quad owns k = kc*32+quad*8+j
//   -> per-lane 8 contiguous bytes at rg*2048 + kc*512 + lane*8 (one i64 load).
// Same index math as the bf16 version, unit = byte.
// ---------------------------------------------------------------------------

// Kernel 1: fp32 -> fp8 e4m3 (*sqrt2) into packed layout + row norms + min init.
// One block per 16-row group. Thread t: row r=t&15, k-chunk c=t>>4 (8 elems).
__global__ __launch_bounds__(256) void prep_kernel(
    const float* __restrict__ X, const float* __restrict__ Y,
    unsigned char* __restrict__ Xb, unsigned char* __restrict__ Yb,
    float* __restrict__ x2, float* __restrict__ y2,
    int* __restrict__ rowmin, int* __restrict__ colmin)
{
    const int which = blockIdx.y;
    const float* __restrict__ src = which ? Y : X;
    unsigned char* __restrict__ dst = which ? Yb : Xb;
    float* __restrict__ nrm = which ? y2 : x2;
    int* __restrict__ mn = which ? colmin : rowmin;

    const int t = threadIdx.x;
    const int r = t & 15, c = t >> 4;          // c in 0..15
    const int rgG = blockIdx.x;                // global row-group
    const int row = rgG * 16 + r;

    const float4 v0 = *(const float4*)(src + (size_t)row * D_ + c * 8);
    const float4 v1 = *(const float4*)(src + (size_t)row * D_ + c * 8 + 4);

    float sq = v0.x * v0.x;
    sq = fmaf(v0.y, v0.y, sq); sq = fmaf(v0.z, v0.z, sq); sq = fmaf(v0.w, v0.w, sq);
    sq = fmaf(v1.x, v1.x, sq); sq = fmaf(v1.y, v1.y, sq);
    sq = fmaf(v1.z, v1.z, sq); sq = fmaf(v1.w, v1.w, sq);

    // fp8 e4m3 (OCP on gfx950) of v*sqrt2, 4 per uint
    unsigned lo = 0, hi = 0;
    lo = __builtin_amdgcn_cvt_pk_fp8_f32(v0.x * SQRT2, v0.y * SQRT2, lo, false);
    lo = __builtin_amdgcn_cvt_pk_fp8_f32(v0.z * SQRT2, v0.w * SQRT2, lo, true);
    hi = __builtin_amdgcn_cvt_pk_fp8_f32(v1.x * SQRT2, v1.y * SQRT2, hi, false);
    hi = __builtin_amdgcn_cvt_pk_fp8_f32(v1.z * SQRT2, v1.w * SQRT2, hi, true);

    const int b = row >> 12;
    const int rg = (row & (N_ - 1)) >> 4;
    uint2 packed; packed.x = lo; packed.y = hi;
    *(uint2*)(dst + (size_t)b * EPB + rg * 2048 + c * 128 + r * 8) = packed;

    __shared__ float s[256];
    s[r * 16 + c] = sq;
    __syncthreads();
    if (t < 16) {
        const float4* sp = (const float4*)(s + t * 16);
        float4 a = sp[0], bq = sp[1], cq = sp[2], d = sp[3];
        float tot = a.x + a.y + a.z + a.w + bq.x + bq.y + bq.z + bq.w
                  + cq.x + cq.y + cq.z + cq.w + d.x + d.y + d.z + d.w;
        nrm[rgG * 16 + t] = tot;
        mn[rgG * 16 + t] = 0x7f7fffff;   // +FLT_MAX bits
    }
}

// ---------------------------------------------------------------------------
// Kernel 2: stripe-sweep fp8 MFMA chamfer. NO LDS, NO barriers, NO spill.
// Block = 4 waves; rows iT*128 + (wave>>1)*64; sweeps 4 steps of 128 cols
// (jc = 512-col chunk). A-frags resident (16 x i64 = 32 VGPR); per step all
// 16 B-frags issued before the MFMA burst (32 VGPR, max loads in flight).
// Grid x = jc -> all blocks of a col-chunk land on one XCD (round-robin %8):
// B reads are XCD-L2-local.
//   acc == 2*zz (inputs pre-scaled by sqrt2); P = x2 + y2 - acc.
//   C/D layout: row = quad*4 + reg, col = l16   [m89; dtype-independent]
// ---------------------------------------------------------------------------
__global__ __launch_bounds__(256, 2) void chamfer_mfma(
    const unsigned char* __restrict__ Xb, const unsigned char* __restrict__ Yb,
    const float* __restrict__ x2, const float* __restrict__ y2,
    int* __restrict__ rowmin, int* __restrict__ colmin)
{
    const int b = blockIdx.z;
    const int iT = blockIdx.y;           // 0..31
    const int jc = blockIdx.x;           // 0..7   (512-col chunk)
    const int tid = threadIdx.x;
    const int wave = tid >> 6, lane = tid & 63;
    const int quad = lane >> 4, l16 = lane & 15;
    const int wr = wave >> 1, wc = wave & 1;
    const int rowBase = iT * 128 + wr * 64;

    const unsigned char* __restrict__ Xp = Xb + (size_t)b * EPB;
    const unsigned char* __restrict__ Yp = Yb + (size_t)b * EPB;

    // ---- A fragments resident (16 x i64 = 32 VGPR) ----
    long af[4][4];   // [rt][kc]
    #pragma unroll
    for (int rt = 0; rt < 4; rt++) {
        const unsigned char* ap = Xp + ((rowBase >> 4) + rt) * 2048 + lane * 8;
        #pragma unroll
        for (int kc = 0; kc < 4; kc++)
            af[rt][kc] = *(const long*)(ap + kc * 512);
    }
    float x2v[4][4];   // row = rowBase + rt*16 + quad*4 + i
    #pragma unroll
    for (int rt = 0; rt < 4; rt++)
        #pragma unroll
        for (int i = 0; i < 4; i++)
            x2v[rt][i] = x2[(size_t)b * N_ + rowBase + rt * 16 + quad * 4 + i];

    float rmin[4][4];
    #pragma unroll
    for (int rt = 0; rt < 4; rt++)
        #pragma unroll
        for (int i = 0; i < 4; i++) rmin[rt][i] = 3.0e38f;

    for (int s = 0; s < 4; ++s) {
        const int colBase = jc * 512 + s * 128 + wc * 64;
        const int cg = colBase >> 4;               // column row-group index

        float y2v[4];
        #pragma unroll
        for (int ct = 0; ct < 4; ct++)
            y2v[ct] = y2[(size_t)b * N_ + colBase + ct * 16 + l16];

        // issue ALL 16 B-fragment loads before the MFMA burst
        long bfv[4][4];
        #pragma unroll
        for (int ct = 0; ct < 4; ct++) {
            const unsigned char* bp = Yp + (size_t)(cg + ct) * 2048 + lane * 8;
            #pragma unroll
            for (int kc = 0; kc < 4; kc++)
                bfv[ct][kc] = *(const long*)(bp + kc * 512);
        }

        f32x4 acc[4][4];
        #pragma unroll
        for (int i = 0; i < 4; i++)
            #pragma unroll
            for (int j = 0; j < 4; j++)
                acc[i][j] = (f32x4){0.f, 0.f, 0.f, 0.f};

        #pragma unroll
        for (int kc = 0; kc < 4; kc++)
            #pragma unroll
            for (int rt = 0; rt < 4; rt++)
                #pragma unroll
                for (int ct = 0; ct < 4; ct++)
                    acc[rt][ct] = __builtin_amdgcn_mfma_f32_16x16x32_fp8_fp8(
                        af[rt][kc], bfv[ct][kc], acc[rt][ct], 0, 0, 0);

        // ---- fold: rmin over cols (persist); cmin over rows (emit now) ----
        float cmin[4];
        #pragma unroll
        for (int ct = 0; ct < 4; ct++) cmin[ct] = 3.0e38f;
        #pragma unroll
        for (int rt = 0; rt < 4; rt++)
            #pragma unroll
            for (int i = 0; i < 4; i++) {
                const float xv = x2v[rt][i];
                float rm = rmin[rt][i];
                #pragma unroll
                for (int ct = 0; ct < 4; ct++) {
                    const float a = acc[rt][ct][i];
                    rm = fminf(rm, y2v[ct] - a);
                    cmin[ct] = fminf(cmin[ct], xv - a);
                }
                rmin[rt][i] = rm;
            }
        #pragma unroll
        for (int ct = 0; ct < 4; ct++) {
            float v = cmin[ct];
            v = fminf(v, __shfl_xor(v, 16));
            v = fminf(v, __shfl_xor(v, 32));
            if (quad == 0)
                atomicMin(&colmin[(size_t)b * N_ + colBase + ct * 16 + l16],
                          __float_as_int(v + COFF));
        }
    }

    // ---- rowmin emission (once per block) ----
    #pragma unroll
    for (int rt = 0; rt < 4; rt++)
        #pragma unroll
        for (int i = 0; i < 4; i++) {
            float v = rmin[rt][i];
            #pragma unroll
            for (int m = 1; m < 16; m <<= 1) v = fminf(v, __shfl_xor(v, m));
            if (l16 == 0) {
                float c = fminf(fmaxf(x2v[rt][i] + v, 0.0f), 100.0f);
                atomicMin(&rowmin[(size_t)b * N_ + rowBase + rt * 16 + quad * 4 + i],
                          __float_as_int(c));
            }
        }
}

// ---------------------------------------------------------------------------
// Kernel 3: final mean, single 1024-thread block, direct write (no atomics,
// no memset dispatch). rowmin holds clamped values; colmin holds
// (min_i(x2_i - acc) + COFF): add y2, subtract COFF, clamp here.
// ---------------------------------------------------------------------------
__global__ __launch_bounds__(1024) void finalize_kernel(
    const int* __restrict__ rowmin, const int* __restrict__ colmin,
    const float* __restrict__ y2, float* __restrict__ out)
{
    float s = 0.f;
    for (int i = threadIdx.x; i < B_ * N_ / 4; i += 1024) {
        int4 v = ((const int4*)rowmin)[i];
        s += __int_as_float(v.x) + __int_as_float(v.y) +
             __int_as_float(v.z) + __int_as_float(v.w);
        int4 c = ((const int4*)colmin)[i];
        float4 yv = ((const float4*)y2)[i];
        s += fminf(fmaxf(__int_as_float(c.x) - COFF + yv.x, 0.f), 100.f);
        s += fminf(fmaxf(__int_as_float(c.y) - COFF + yv.y, 0.f), 100.f);
        s += fminf(fmaxf(__int_as_float(c.z) - COFF + yv.z, 0.f), 100.f);
        s += fminf(fmaxf(__int_as_float(c.w) - COFF + yv.w, 0.f), 100.f);
    }
    #pragma unroll
    for (int m = 1; m < 64; m <<= 1) s += __shfl_xor(s, m);
    __shared__ float sm[16];
    if ((threadIdx.x & 63) == 0) sm[threadIdx.x >> 6] = s;
    __syncthreads();
    if (threadIdx.x == 0) {
        float t = 0.f;
        #pragma unroll
        for (int i = 0; i < 16; i++) t += sm[i];
        out[0] = t / ((float)B_ * (float)N_) / (float)B_;
    }
}

extern "C" void kernel_launch(void* const* d_in, const int* in_sizes, int n_in,
                              void* d_out, int out_size, void* d_ws, size_t ws_size,
                              hipStream_t stream) {
    const float* X = (const float*)d_in[0];   // corr_pred   [B,N,D] fp32
    const float* Y = (const float*)d_in[1];   // corr_target [B,N,D] fp32

    char* ws = (char*)d_ws;
    const size_t f8_bytes = (size_t)B_ * N_ * D_;       // 2 MB each (packed fp8)
    unsigned char* Xb = (unsigned char*)ws;
    unsigned char* Yb = (unsigned char*)(ws + f8_bytes);
    char* ws2 = ws + 2 * f8_bytes;
    const size_t vec_bytes = (size_t)B_ * N_ * 4;       // 64 KB each
    float* x2     = (float*)(ws2);
    float* y2     = (float*)(ws2 + vec_bytes);
    int*   rowmin = (int*)  (ws2 + 2 * vec_bytes);
    int*   colmin = (int*)  (ws2 + 3 * vec_bytes);
    float* out = (float*)d_out;

    prep_kernel<<<dim3(B_ * N_ / 16, 2), 256, 0, stream>>>(
        X, Y, Xb, Yb, x2, y2, rowmin, colmin);
    chamfer_mfma<<<dim3(8, N_ / 128, B_), 256, 0, stream>>>(
        Xb, Yb, x2, y2, rowmin, colmin);
    finalize_kernel<<<1, 1024, 0, stream>>>(rowmin, colmin, y2, out);
}

// Round 8
// 95.235 us; speedup vs baseline: 1.9304x; 1.0069x over previous
//
#include <hip/hip_runtime.h>
#include <hip/hip_bf16.h>

#define B_ 4
#define N_ 4096
#define D_ 128
#define EPB (N_ * D_)        // BYTES per batch in packed fp8 layout = 524288
#define COFF 1024.0f         // colmin positivity offset

typedef float f32x4 __attribute__((ext_vector_type(4)));

#define SQRT2 1.41421356237309515f

// ---------------------------------------------------------------------------
// Packed fragment-major fp8 layout (per batch, BYTE addresses):
//   elem(row, k) -> (row>>4)*2048 + (k>>3)*128 + (row&15)*8 + (k&7)
// MFMA fragment (16x16x32 fp8): lane l16 = row, quad owns k = kc*32+quad*8+j
//   -> per-lane 8 contiguous bytes at rg*2048 + kc*512 + lane*8 (one i64 load).
// ---------------------------------------------------------------------------

// Kernel 1: fp32 -> fp8 e4m3 (*sqrt2) into packed layout + row norms + min init.
__global__ __launch_bounds__(256) void prep_kernel(
    const float* __restrict__ X, const float* __restrict__ Y,
    unsigned char* __restrict__ Xb, unsigned char* __restrict__ Yb,
    float* __restrict__ x2, float* __restrict__ y2,
    int* __restrict__ rowmin, int* __restrict__ colmin)
{
    const int which = blockIdx.y;
    const float* __restrict__ src = which ? Y : X;
    unsigned char* __restrict__ dst = which ? Yb : Xb;
    float* __restrict__ nrm = which ? y2 : x2;
    int* __restrict__ mn = which ? colmin : rowmin;

    const int t = threadIdx.x;
    const int r = t & 15, c = t >> 4;          // c in 0..15
    const int rgG = blockIdx.x;                // global row-group
    const int row = rgG * 16 + r;

    const float4 v0 = *(const float4*)(src + (size_t)row * D_ + c * 8);
    const float4 v1 = *(const float4*)(src + (size_t)row * D_ + c * 8 + 4);

    float sq = v0.x * v0.x;
    sq = fmaf(v0.y, v0.y, sq); sq = fmaf(v0.z, v0.z, sq); sq = fmaf(v0.w, v0.w, sq);
    sq = fmaf(v1.x, v1.x, sq); sq = fmaf(v1.y, v1.y, sq);
    sq = fmaf(v1.z, v1.z, sq); sq = fmaf(v1.w, v1.w, sq);

    unsigned lo = 0, hi = 0;
    lo = __builtin_amdgcn_cvt_pk_fp8_f32(v0.x * SQRT2, v0.y * SQRT2, lo, false);
    lo = __builtin_amdgcn_cvt_pk_fp8_f32(v0.z * SQRT2, v0.w * SQRT2, lo, true);
    hi = __builtin_amdgcn_cvt_pk_fp8_f32(v1.x * SQRT2, v1.y * SQRT2, hi, false);
    hi = __builtin_amdgcn_cvt_pk_fp8_f32(v1.z * SQRT2, v1.w * SQRT2, hi, true);

    const int b = row >> 12;
    const int rg = (row & (N_ - 1)) >> 4;
    uint2 packed; packed.x = lo; packed.y = hi;
    *(uint2*)(dst + (size_t)b * EPB + rg * 2048 + c * 128 + r * 8) = packed;

    __shared__ float s[256];
    s[r * 16 + c] = sq;
    __syncthreads();
    if (t < 16) {
        const float4* sp = (const float4*)(s + t * 16);
        float4 a = sp[0], bq = sp[1], cq = sp[2], d = sp[3];
        float tot = a.x + a.y + a.z + a.w + bq.x + bq.y + bq.z + bq.w
                  + cq.x + cq.y + cq.z + cq.w + d.x + d.y + d.z + d.w;
        nrm[rgG * 16 + t] = tot;
        mn[rgG * 16 + t] = 0x7f7fffff;   // +FLT_MAX bits
    }
}

// ---------------------------------------------------------------------------
// Kernel 2: stripe-sweep fp8 MFMA chamfer. NO LDS, NO barriers, NO spill.
// Block = 4 waves x 64 DISTINCT rows = 256-row stripe (grid y = 16).
// Sweeps 8 steps of 64 cols (jc = 512-col chunk). All 4 waves read the SAME
// 8 KB B-slice per step -> L1 dedups; B re-read/batch drops 32x+dup -> 16x.
// A-frags resident (16 x i64 = 32 VGPR); B-frags 16 x i64 per step.
// Grid x = jc -> col-chunk maps to one XCD (round-robin %8): B XCD-L2-local.
//   acc == 2*zz (inputs pre-scaled by sqrt2); P = x2 + y2 - acc.
//   C/D layout: row = quad*4 + reg, col = l16   [m89; dtype-independent]
// ---------------------------------------------------------------------------
__global__ __launch_bounds__(256, 2) void chamfer_mfma(
    const unsigned char* __restrict__ Xb, const unsigned char* __restrict__ Yb,
    const float* __restrict__ x2, const float* __restrict__ y2,
    int* __restrict__ rowmin, int* __restrict__ colmin)
{
    const int b = blockIdx.z;
    const int iT = blockIdx.y;           // 0..15  (256-row stripe)
    const int jc = blockIdx.x;           // 0..7   (512-col chunk)
    const int tid = threadIdx.x;
    const int wave = tid >> 6, lane = tid & 63;
    const int quad = lane >> 4, l16 = lane & 15;
    const int rowBase = iT * 256 + wave * 64;

    const unsigned char* __restrict__ Xp = Xb + (size_t)b * EPB;
    const unsigned char* __restrict__ Yp = Yb + (size_t)b * EPB;

    // ---- A fragments resident (16 x i64 = 32 VGPR) ----
    long af[4][4];   // [rt][kc]
    #pragma unroll
    for (int rt = 0; rt < 4; rt++) {
        const unsigned char* ap = Xp + ((rowBase >> 4) + rt) * 2048 + lane * 8;
        #pragma unroll
        for (int kc = 0; kc < 4; kc++)
            af[rt][kc] = *(const long*)(ap + kc * 512);
    }
    float x2v[4][4];   // row = rowBase + rt*16 + quad*4 + i
    #pragma unroll
    for (int rt = 0; rt < 4; rt++)
        #pragma unroll
        for (int i = 0; i < 4; i++)
            x2v[rt][i] = x2[(size_t)b * N_ + rowBase + rt * 16 + quad * 4 + i];

    float rmin[4][4];
    #pragma unroll
    for (int rt = 0; rt < 4; rt++)
        #pragma unroll
        for (int i = 0; i < 4; i++) rmin[rt][i] = 3.0e38f;

    for (int s = 0; s < 8; ++s) {
        const int colBase = jc * 512 + s * 64;
        const int cg = colBase >> 4;               // column row-group index

        float y2v[4];
        #pragma unroll
        for (int ct = 0; ct < 4; ct++)
            y2v[ct] = y2[(size_t)b * N_ + colBase + ct * 16 + l16];

        // issue ALL 16 B-fragment loads before the MFMA burst
        long bfv[4][4];
        #pragma unroll
        for (int ct = 0; ct < 4; ct++) {
            const unsigned char* bp = Yp + (size_t)(cg + ct) * 2048 + lane * 8;
            #pragma unroll
            for (int kc = 0; kc < 4; kc++)
                bfv[ct][kc] = *(const long*)(bp + kc * 512);
        }

        f32x4 acc[4][4];
        #pragma unroll
        for (int i = 0; i < 4; i++)
            #pragma unroll
            for (int j = 0; j < 4; j++)
                acc[i][j] = (f32x4){0.f, 0.f, 0.f, 0.f};

        #pragma unroll
        for (int kc = 0; kc < 4; kc++)
            #pragma unroll
            for (int rt = 0; rt < 4; rt++)
                #pragma unroll
                for (int ct = 0; ct < 4; ct++)
                    acc[rt][ct] = __builtin_amdgcn_mfma_f32_16x16x32_fp8_fp8(
                        af[rt][kc], bfv[ct][kc], acc[rt][ct], 0, 0, 0);

        // ---- fold: rmin over cols (persist); cmin over rows (emit now) ----
        float cmin[4];
        #pragma unroll
        for (int ct = 0; ct < 4; ct++) cmin[ct] = 3.0e38f;
        #pragma unroll
        for (int rt = 0; rt < 4; rt++)
            #pragma unroll
            for (int i = 0; i < 4; i++) {
                const float xv = x2v[rt][i];
                float rm = rmin[rt][i];
                #pragma unroll
                for (int ct = 0; ct < 4; ct++) {
                    const float a = acc[rt][ct][i];
                    rm = fminf(rm, y2v[ct] - a);
                    cmin[ct] = fminf(cmin[ct], xv - a);
                }
                rmin[rt][i] = rm;
            }
        #pragma unroll
        for (int ct = 0; ct < 4; ct++) {
            float v = cmin[ct];
            v = fminf(v, __shfl_xor(v, 16));
            v = fminf(v, __shfl_xor(v, 32));
            if (quad == 0)
                atomicMin(&colmin[(size_t)b * N_ + colBase + ct * 16 + l16],
                          __float_as_int(v + COFF));
        }
    }

    // ---- rowmin emission (once per block) ----
    #pragma unroll
    for (int rt = 0; rt < 4; rt++)
        #pragma unroll
        for (int i = 0; i < 4; i++) {
            float v = rmin[rt][i];
            #pragma unroll
            for (int m = 1; m < 16; m <<= 1) v = fminf(v, __shfl_xor(v, m));
            if (l16 == 0) {
                float c = fminf(fmaxf(x2v[rt][i] + v, 0.0f), 100.0f);
                atomicMin(&rowmin[(size_t)b * N_ + rowBase + rt * 16 + quad * 4 + i],
                          __float_as_int(c));
            }
        }
}

// ---------------------------------------------------------------------------
// Kernel 3: final mean, single 1024-thread block, direct write.
// rowmin holds clamped values; colmin holds (min_i(x2_i - acc) + COFF):
// add y2, subtract COFF, clamp here.
// ---------------------------------------------------------------------------
__global__ __launch_bounds__(1024) void finalize_kernel(
    const int* __restrict__ rowmin, const int* __restrict__ colmin,
    const float* __restrict__ y2, float* __restrict__ out)
{
    float s = 0.f;
    for (int i = threadIdx.x; i < B_ * N_ / 4; i += 1024) {
        int4 v = ((const int4*)rowmin)[i];
        s += __int_as_float(v.x) + __int_as_float(v.y) +
             __int_as_float(v.z) + __int_as_float(v.w);
        int4 c = ((const int4*)colmin)[i];
        float4 yv = ((const float4*)y2)[i];
        s += fminf(fmaxf(__int_as_float(c.x) - COFF + yv.x, 0.f), 100.f);
        s += fminf(fmaxf(__int_as_float(c.y) - COFF + yv.y, 0.f), 100.f);
        s += fminf(fmaxf(__int_as_float(c.z) - COFF + yv.z, 0.f), 100.f);
        s += fminf(fmaxf(__int_as_float(c.w) - COFF + yv.w, 0.f), 100.f);
    }
    #pragma unroll
    for (int m = 1; m < 64; m <<= 1) s += __shfl_xor(s, m);
    __shared__ float sm[16];
    if ((threadIdx.x & 63) == 0) sm[threadIdx.x >> 6] = s;
    __syncthreads();
    if (threadIdx.x == 0) {
        float t = 0.f;
        #pragma unroll
        for (int i = 0; i < 16; i++) t += sm[i];
        out[0] = t / ((float)B_ * (float)N_) / (float)B_;
    }
}

extern "C" void kernel_launch(void* const* d_in, const int* in_sizes, int n_in,
                              void* d_out, int out_size, void* d_ws, size_t ws_size,
                              hipStream_t stream) {
    const float* X = (const float*)d_in[0];   // corr_pred   [B,N,D] fp32
    const float* Y = (const float*)d_in[1];   // corr_target [B,N,D] fp32

    char* ws = (char*)d_ws;
    const size_t f8_bytes = (size_t)B_ * N_ * D_;       // 2 MB each (packed fp8)
    unsigned char* Xb = (unsigned char*)ws;
    unsigned char* Yb = (unsigned char*)(ws + f8_bytes);
    char* ws2 = ws + 2 * f8_bytes;
    const size_t vec_bytes = (size_t)B_ * N_ * 4;       // 64 KB each
    float* x2     = (float*)(ws2);
    float* y2     = (float*)(ws2 + vec_bytes);
    int*   rowmin = (int*)  (ws2 + 2 * vec_bytes);
    int*   colmin = (int*)  (ws2 + 3 * vec_bytes);
    float* out = (float*)d_out;

    prep_kernel<<<dim3(B_ * N_ / 16, 2), 256, 0, stream>>>(
        X, Y, Xb, Yb, x2, y2, rowmin, colmin);
    chamfer_mfma<<<dim3(8, N_ / 256, B_), 256, 0, stream>>>(
        Xb, Yb, x2, y2, rowmin, colmin);
    finalize_kernel<<<1, 1024, 0, stream>>>(rowmin, colmin, y2, out);
}